// Round 8
// baseline (109.317 us; speedup 1.0000x reference)
//
#include <hip/hip_runtime.h>
#include <hip/hip_fp16.h>
#include <math.h>

// Problem constants: B=8, T=64, R=100, TH=768, IH=1024, P=N=512
#define B_  8
#define T_  64
#define R_  100
#define TH_ 768
#define IH_ 1024
#define P_  512
#define N_  512

#define CTANH 2.88539008177792681f   // 2*log2(e): tanh(x) = 1 - 2/(1+exp2(CTANH*x))

typedef short short8  __attribute__((ext_vector_type(8)));
typedef float floatx4 __attribute__((ext_vector_type(4)));

// pack two f32 -> two bf16 (round-half-up) in one dword: lo=x, hi=y
__device__ __forceinline__ unsigned int bfpack(float x, float y) {
  union { float f; unsigned int u; } a, b; a.f = x; b.f = y;
  return ((a.u + 0x8000u) >> 16) | ((b.u + 0x8000u) & 0xFFFF0000u);
}

// ---------------------------------------------------------------------------
// Direct-MFMA GEMM + bias + exact GELU -> f16 (pre-scaled by CTANH).
// ZERO LDS, ZERO barriers. One wave = one 16x16 output tile.
// Waves 0..1023: Q gemm (32 mt x 32 nt, K=768); 1024..2623: K gemm (50 x 32,
// K=1024). 656 blocks x 256 thr = 2624 waves (~2.6/SIMD), each a pure ILP
// pipeline: per k-step 2x dwordx4 (A) + 8x dword (B, L2-resident) -> bf16
// pack -> mfma_f32_16x16x32_bf16. Unroll 4 keeps ~40 loads in flight.
// Rationale: both prior GEMMs were serial-latency-bound on the
// [stage->barrier->mfma->barrier] chain; this removes the chain entirely.
// ---------------------------------------------------------------------------
__global__ __launch_bounds__(256) void gemm_direct(
    const float* __restrict__ encT, const float* __restrict__ Wq,
    const float* __restrict__ bq, __half* __restrict__ qout,
    const float* __restrict__ encI, const float* __restrict__ Wk,
    const float* __restrict__ bk, __half* __restrict__ kout) {
  const int wid  = blockIdx.x * 4 + (threadIdx.x >> 6);
  const int lane = threadIdx.x & 63;
  const int m16  = lane & 15;
  const int quad = lane >> 4;

  const float* __restrict__ X;
  const float* __restrict__ W;
  const float* __restrict__ bias;
  __half* __restrict__ Y;
  int KD, mt, nt;
  if (wid < 1024) {            // block-uniform branch (1024/4 = 256 blocks)
    X = encT; W = Wq; bias = bq; Y = qout; KD = TH_;
    mt = wid >> 5; nt = wid & 31;
  } else {
    const int w2 = wid - 1024;
    X = encI; W = Wk; bias = bk; Y = kout; KD = IH_;
    mt = w2 >> 5; nt = w2 & 31;
  }

  // A: lane reads row (mt*16 + m16), k = kt*32 + quad*8 + [0..7]
  const float* __restrict__ Ap = X + (size_t)(mt * 16 + m16) * KD + quad * 8;
  // B: lane reads col (nt*16 + m16), k rows quad*8 + [0..7] (+ kt*32)
  const float* __restrict__ Bp = W + (size_t)(quad * 8) * N_ + nt * 16 + m16;

  floatx4 acc = {0.f, 0.f, 0.f, 0.f};
  const int nk = KD >> 5;              // 24 or 32, divisible by 4

  #pragma unroll 4
  for (int kt = 0; kt < nk; ++kt) {
    float4 a0 = *(const float4*)(Ap + kt * 32);
    float4 a1 = *(const float4*)(Ap + kt * 32 + 4);
    float b0 = Bp[((size_t)kt * 32 + 0) * N_];
    float b1 = Bp[((size_t)kt * 32 + 1) * N_];
    float b2 = Bp[((size_t)kt * 32 + 2) * N_];
    float b3 = Bp[((size_t)kt * 32 + 3) * N_];
    float b4 = Bp[((size_t)kt * 32 + 4) * N_];
    float b5 = Bp[((size_t)kt * 32 + 5) * N_];
    float b6 = Bp[((size_t)kt * 32 + 6) * N_];
    float b7 = Bp[((size_t)kt * 32 + 7) * N_];

    union { unsigned int u[4]; short8 s; } af, bf;
    af.u[0] = bfpack(a0.x, a0.y);
    af.u[1] = bfpack(a0.z, a0.w);
    af.u[2] = bfpack(a1.x, a1.y);
    af.u[3] = bfpack(a1.z, a1.w);
    bf.u[0] = bfpack(b0, b1);
    bf.u[1] = bfpack(b2, b3);
    bf.u[2] = bfpack(b4, b5);
    bf.u[3] = bfpack(b6, b7);

    acc = __builtin_amdgcn_mfma_f32_16x16x32_bf16(af.s, bf.s, acc, 0, 0, 0);
  }

  // epilogue: D layout col=lane&15, row=quad*4+reg (m89-verified).
  const float is2 = 0.70710678118654752f;
  const int col = nt * 16 + m16;
  const float bia = bias[col];
  #pragma unroll
  for (int i = 0; i < 4; ++i) {
    const int row = mt * 16 + quad * 4 + i;
    float v = acc[i] + bia;
    v = CTANH * 0.5f * v * (1.f + erff(v * is2));
    Y[(size_t)row * N_ + col] = __float2half(v);
  }
}

// ---------------------------------------------------------------------------
// Fusion on f16 q/k — BYTE-IDENTICAL to round 6 (single-variable discipline).
// out[b,t,r] = sum_p w*(1 - 2/(1+exp2(q'+k'))) + b + mask.
// One wave = one rg (4 r's, 16 lanes each, 32 p/lane). Grid (512, 7).
// ---------------------------------------------------------------------------
__global__ __launch_bounds__(256) void fuse_kernel_h(
    const __half* __restrict__ q, const __half* __restrict__ k,
    const float* __restrict__ w, const float* __restrict__ bscalar,
    const float* __restrict__ mask, float* __restrict__ out) {
  const int bt = blockIdx.x;               // 0..511
  const int wave = threadIdx.x >> 6;
  const int rg = blockIdx.y * 4 + wave;    // 0..27
  if (rg >= 25) return;                    // whole-wave exit; no barriers used
  const int lane = threadIdx.x & 63;
  const int sub  = lane >> 4;              // r within group of 4
  const int pi   = lane & 15;              // p-slice
  const int r = rg * 4 + sub;              // 0..99
  const int b = bt >> 6;

  const __half* __restrict__ qp = q + (size_t)bt * P_ + pi * 8;
  const __half* __restrict__ kp = k + (size_t)(b * R_ + r) * P_ + pi * 8;
  const float* __restrict__ wp = w + pi * 8;

  float acc0 = 0.f, acc1 = 0.f;
  #pragma unroll
  for (int i = 0; i < 4; ++i) {
    union { float4 f; __half2 h[4]; } qu, ku;
    qu.f = *(const float4*)(qp + i * 128);
    ku.f = *(const float4*)(kp + i * 128);
    float4 w0 = *(const float4*)(wp + i * 128);
    float4 w1 = *(const float4*)(wp + i * 128 + 4);
    #pragma unroll
    for (int e = 0; e < 4; ++e) {
      __half2 s = __hadd2(qu.h[e], ku.h[e]);
      float x0 = __low2float(s);
      float x1 = __high2float(s);
      float d0 = __builtin_amdgcn_rcpf(1.f + __builtin_amdgcn_exp2f(x0));
      float d1 = __builtin_amdgcn_rcpf(1.f + __builtin_amdgcn_exp2f(x1));
      float s0 = fmaf(-2.f, d0, 1.f);
      float s1 = fmaf(-2.f, d1, 1.f);
      const float we0 = (e == 0) ? w0.x : (e == 1) ? w0.z : (e == 2) ? w1.x : w1.z;
      const float we1 = (e == 0) ? w0.y : (e == 1) ? w0.w : (e == 2) ? w1.y : w1.w;
      acc0 = fmaf(we0, s0, acc0);
      acc1 = fmaf(we1, s1, acc1);
    }
  }
  float acc = acc0 + acc1;
  #pragma unroll
  for (int off = 1; off < 16; off <<= 1) acc += __shfl_xor(acc, off, 64);

  if (pi == 0) {
    out[(size_t)bt * R_ + r] = acc + bscalar[0] + mask[(size_t)bt * R_ + r];
  }
}

// ---------------------------------------------------------------------------
extern "C" void kernel_launch(void* const* d_in, const int* in_sizes, int n_in,
                              void* d_out, int out_size, void* d_ws, size_t ws_size,
                              hipStream_t stream) {
  const float* encT = (const float*)d_in[0];
  const float* encI = (const float*)d_in[1];
  const float* mask = (const float*)d_in[2];
  const float* Wq   = (const float*)d_in[3];
  const float* bq   = (const float*)d_in[4];
  const float* Wk   = (const float*)d_in[5];
  const float* bk   = (const float*)d_in[6];
  const float* w    = (const float*)d_in[7];
  const float* bsc  = (const float*)d_in[8];
  float* out = (float*)d_out;

  __half* q = (__half*)d_ws;               // [512, 512] f16, CTANH-prescaled
  __half* k = q + (size_t)B_ * T_ * P_;    // [800, 512] f16, CTANH-prescaled

  gemm_direct<<<dim3(656), 256, 0, stream>>>(encT, Wq, bq, q,
                                             encI, Wk, bk, k);

  fuse_kernel_h<<<dim3(512, 7), 256, 0, stream>>>(q, k, w, bsc, mask, out);
}